// Round 1
// baseline (1294.971 us; speedup 1.0000x reference)
//
#include <hip/hip_runtime.h>

#define B 8
#define C 64
#define N 4096
#define O 64
#define KNN 20
#define BN_EPS 1e-5f
#define NEG_SLOPE 0.2f

// -------- K0: transpose x (B,C,N) -> Xt (B,N,C), compute sq[b][n] = ||x_n||^2
__global__ __launch_bounds__(256) void k_transpose(const float* __restrict__ x,
                                                   float* __restrict__ Xt,
                                                   float* __restrict__ sq) {
    __shared__ float lds[C][65];
    int b    = blockIdx.x >> 6;
    int n0   = (blockIdx.x & 63) << 6;
    int lane = threadIdx.x & 63;
    int w    = threadIdx.x >> 6;
    // load 64x64 tile: wave w loads c rows w*16..w*16+15, lanes along n (coalesced)
    #pragma unroll
    for (int i = 0; i < 16; ++i) {
        int c = w * 16 + i;
        lds[c][lane] = x[(size_t)b * C * N + (size_t)c * N + n0 + lane];
    }
    __syncthreads();
    // store: wave w handles n rows w*16..w*16+15, lanes along c (coalesced)
    #pragma unroll
    for (int i = 0; i < 16; ++i) {
        int nl = w * 16 + i;
        float v = lds[lane][nl];                 // stride 65 -> conflict-free
        Xt[(size_t)b * N * C + (size_t)(n0 + nl) * C + lane] = v;
        float s = v * v;
        #pragma unroll
        for (int off = 32; off; off >>= 1) s += __shfl_xor(s, off, 64);
        if (lane == 0) sq[b * N + n0 + nl] = s;
    }
}

// -------- K1: a = X*(W1-W2)^T, bvec = X*W2^T   (per-lane o, W rows in registers)
__global__ __launch_bounds__(256) void k_ab(const float* __restrict__ Xt,
                                            const float* __restrict__ W,
                                            float* __restrict__ av,
                                            float* __restrict__ bv) {
    int b  = blockIdx.x >> 4;
    int n0 = (blockIdx.x & 15) << 8;
    int o  = threadIdx.x & 63;
    int w  = __builtin_amdgcn_readfirstlane((int)(threadIdx.x >> 6));
    float wa[C], wb[C];
    #pragma unroll
    for (int c = 0; c < C; ++c) {
        float w1 = W[o * 2 * C + c];
        float w2 = W[o * 2 * C + C + c];
        wa[c] = w1 - w2;
        wb[c] = w2;
    }
    const float* xb = Xt + (size_t)b * N * C;
    for (int i = 0; i < 64; ++i) {
        int n = n0 + w * 64 + i;
        const float* xr = xb + (size_t)n * C;    // wave-uniform -> scalar loads
        float aa = 0.f, bb = 0.f;
        #pragma unroll
        for (int c = 0; c < C; ++c) {
            float xc = xr[c];
            aa = fmaf(xc, wa[c], aa);
            bb = fmaf(xc, wb[c], bb);
        }
        size_t oidx = ((size_t)b * N + n) * O + o;
        av[oidx] = aa;
        bv[oidx] = bb;
    }
}

// -------- K2: fused pairwise-inner-product + top-20 (rank r = 2*x_n.x_m - ||x_m||^2)
__global__ __launch_bounds__(256) void k_knn(const float* __restrict__ Xt,
                                             const float* __restrict__ sq,
                                             int* __restrict__ knn) {
    __shared__ float lds_d[4][64][KNN];
    __shared__ int   lds_i[4][64][KNN];
    int b    = blockIdx.x >> 6;
    int n0   = (blockIdx.x & 63) << 6;
    int lane = threadIdx.x & 63;
    int w    = __builtin_amdgcn_readfirstlane((int)(threadIdx.x >> 6));
    int row  = n0 + lane;
    const float* xb  = Xt + (size_t)b * N * C;
    const float* sqb = sq + b * N;
    float q[C];
    #pragma unroll
    for (int c = 0; c < C; ++c) q[c] = xb[(size_t)row * C + c];
    float d[KNN]; int id[KNN];
    #pragma unroll
    for (int j = 0; j < KNN; ++j) { d[j] = -3.4e38f; id[j] = 0; }
    float tmin = -3.4e38f;
    int m0 = w * (N / 4);
    for (int m = m0; m < m0 + N / 4; ++m) {
        const float4* cv = (const float4*)(xb + (size_t)m * C);  // wave-uniform
        float a0 = 0.f, a1 = 0.f, a2 = 0.f, a3 = 0.f;
        #pragma unroll
        for (int cc = 0; cc < C / 4; ++cc) {
            float4 v = cv[cc];
            a0 = fmaf(v.x, q[cc * 4 + 0], a0);
            a1 = fmaf(v.y, q[cc * 4 + 1], a1);
            a2 = fmaf(v.z, q[cc * 4 + 2], a2);
            a3 = fmaf(v.w, q[cc * 4 + 3], a3);
        }
        float r = 2.f * ((a0 + a1) + (a2 + a3)) - sqb[m];
        if (r > tmin) {
            float mv = d[0]; int mp = 0;
            #pragma unroll
            for (int j = 1; j < KNN; ++j) { if (d[j] < mv) { mv = d[j]; mp = j; } }
            #pragma unroll
            for (int j = 0; j < KNN; ++j) { if (j == mp) { d[j] = r; id[j] = m; } }
            float t = d[0];
            #pragma unroll
            for (int j = 1; j < KNN; ++j) t = fminf(t, d[j]);
            tmin = t;
        }
    }
    #pragma unroll
    for (int j = 0; j < KNN; ++j) { lds_d[w][lane][j] = d[j]; lds_i[w][lane][j] = id[j]; }
    __syncthreads();
    if (threadIdx.x < 64) {  // wave 0 merges the 4 partial lists for its row
        #pragma unroll
        for (int ww = 1; ww < 4; ++ww) {
            #pragma unroll
            for (int j = 0; j < KNN; ++j) {
                float r = lds_d[ww][lane][j];
                if (r > tmin) {
                    float mv = d[0]; int mp = 0;
                    #pragma unroll
                    for (int jj = 1; jj < KNN; ++jj) { if (d[jj] < mv) { mv = d[jj]; mp = jj; } }
                    int ri = lds_i[ww][lane][j];
                    #pragma unroll
                    for (int jj = 0; jj < KNN; ++jj) { if (jj == mp) { d[jj] = r; id[jj] = ri; } }
                    float t = d[0];
                    #pragma unroll
                    for (int jj = 1; jj < KNN; ++jj) t = fminf(t, d[jj]);
                    tmin = t;
                }
            }
        }
        int* op = knn + ((size_t)b * N + row) * KNN;
        #pragma unroll
        for (int j = 0; j < KNN; ++j) op[j] = id[j];
    }
}

// -------- K3: out[b][o][n] = leaky(scale*(a[n][o] + max_k bvec[idx_k][o]) + bias)
__global__ __launch_bounds__(256) void k_out(const float* __restrict__ av,
                                             const float* __restrict__ bv,
                                             const int* __restrict__ knn,
                                             const float* __restrict__ gamma,
                                             const float* __restrict__ beta,
                                             const float* __restrict__ rmean,
                                             const float* __restrict__ rvar,
                                             float* __restrict__ out) {
    __shared__ float lds[64][65];
    int b    = blockIdx.x >> 6;
    int n0   = (blockIdx.x & 63) << 6;
    int lane = threadIdx.x & 63;
    int w    = __builtin_amdgcn_readfirstlane((int)(threadIdx.x >> 6));
    int o    = lane;
    float scale = gamma[o] * rsqrtf(rvar[o] + BN_EPS);
    float bias  = fmaf(-rmean[o], scale, beta[o]);
    const float* bvb = bv + (size_t)b * N * O;
    for (int i = 0; i < 16; ++i) {
        int n = n0 + w * 16 + i;
        const int* kn = knn + ((size_t)b * N + n) * KNN;   // wave-uniform
        float mx = -3.4e38f, mn = 3.4e38f;
        #pragma unroll
        for (int j = 0; j < KNN; ++j) {
            float v = bvb[(size_t)kn[j] * O + o];          // coalesced 256B row
            mx = fmaxf(mx, v);
            mn = fminf(mn, v);
        }
        float a   = av[((size_t)b * N + n) * O + o];
        float sel = (scale >= 0.f) ? (a + mx) : (a + mn);  // monotone fold of max_k
        float y   = fmaf(sel, scale, bias);
        y = fmaxf(y, NEG_SLOPE * y);                       // leaky (0<slope<1)
        lds[o][w * 16 + i] = y;
    }
    __syncthreads();
    int r  = threadIdx.x >> 2;
    int c0 = (threadIdx.x & 3) << 4;
    float* ob = out + (size_t)b * O * N + (size_t)r * N + n0;
    #pragma unroll
    for (int j = 0; j < 16; j += 4) {
        float4 v;
        v.x = lds[r][c0 + j + 0];
        v.y = lds[r][c0 + j + 1];
        v.z = lds[r][c0 + j + 2];
        v.w = lds[r][c0 + j + 3];
        *(float4*)(ob + c0 + j) = v;
    }
}

extern "C" void kernel_launch(void* const* d_in, const int* in_sizes, int n_in,
                              void* d_out, int out_size, void* d_ws, size_t ws_size,
                              hipStream_t stream) {
    const float* x     = (const float*)d_in[0];
    const float* W     = (const float*)d_in[1];
    const float* gamma = (const float*)d_in[2];
    const float* beta  = (const float*)d_in[3];
    const float* rmean = (const float*)d_in[4];
    const float* rvar  = (const float*)d_in[5];
    float* out = (float*)d_out;

    float* ws  = (float*)d_ws;
    float* Xt  = ws;                       // 2097152 floats
    float* sqn = ws + 2097152;             // 32768
    float* av  = ws + 2129920;             // 2097152
    float* bvv = ws + 4227072;             // 2097152
    int*   knn = (int*)(ws + 6324224);     // 655360 ints  (total ~28 MB)

    k_transpose<<<512, 256, 0, stream>>>(x, Xt, sqn);
    k_ab<<<128, 256, 0, stream>>>(Xt, W, av, bvv);
    k_knn<<<512, 256, 0, stream>>>(Xt, sqn, knn);
    k_out<<<512, 256, 0, stream>>>(av, bvv, knn, gamma, beta, rmean, rvar, out);
}